// Round 1
// baseline (71.472 us; speedup 1.0000x reference)
//
#include <hip/hip_runtime.h>
#include <math.h>

// Problem constants
constexpr int IMG     = 384;
constexpr int NPIX    = IMG * IMG;        // 147456
constexpr int TM1     = 10;               // T-1
constexpr int NIMG    = 80;               // B * (T-1)
constexpr int THREADS = 256;
constexpr int PXT     = 4;                // pixels per thread
constexpr int PXB     = THREADS * PXT;    // 1024 pixels per block
constexpr int NBX     = NPIX / PXB;       // 144 (exact)
constexpr long long NMASK = (long long)NIMG * NPIX;  // 11,796,480

// Output layout: [0..6] = 7 scalar costs
//   lane, vehicle, green, yellow, red, pedestrian, offroad
// then mask_car[NMASK], mask_side[NMASK], mask_light[NMASK]

__global__ __launch_bounds__(THREADS) void cost_main(
    const float* __restrict__ loc,    // (8,11,2)
    const float* __restrict__ yaw,    // (8,11,1)
    const float* __restrict__ speed,  // (8,11,1)
    const float* __restrict__ bev,    // (8,11,8,384,384)
    float* __restrict__ out)
{
    const int img = blockIdx.y;          // 0..79
    const int b   = img / TM1;
    const int t   = img - b * TM1;       // 0..9 -> bev time index t+1
    const int tid = threadIdx.x;

    // ---- per-image scalars (mirror reference fp order) ----
    const float yaw0 = yaw[b * 11];
    const float c0 = cosf(yaw0), s0 = sinf(yaw0);
    const float rx = loc[(b * 11 + t + 1) * 2 + 0] - loc[b * 22 + 0];
    const float ry = loc[(b * 11 + t + 1) * 2 + 1] - loc[b * 22 + 1];
    const float x  =  c0 * rx + s0 * ry;
    const float yy = -s0 * rx + c0 * ry;
    const float yw = yaw[b * 11 + t + 1] - yaw0;
    const float c = cosf(yw), s = sinf(yw);
    const float sp  = speed[b * 11 + t + 1];
    const float dy  = 1.5f * (fmaxf(10.0f, sp) + 4.9f) + 1.0f;
    const float dyl = sp * 0.5f + 14.7f;            // speed*0.5 + VEH_L*3
    const float xl = x + 12.0f, yl = yy + 3.25f;    // light offset position

    const float* bp = bev + (size_t)((b * 11 + t + 1) * 8) * NPIX;
    float* ocar   = out + 7 + (size_t)img * NPIX;
    float* oside  = ocar + NMASK;
    float* olight = ocar + 2 * NMASK;

    float aL = 0.f, aV = 0.f, aG = 0.f, aY = 0.f, aR = 0.f, aP = 0.f, aO = 0.f;

    const int p0 = blockIdx.x * PXB + tid;
    #pragma unroll
    for (int it = 0; it < PXT; ++it) {
        const int p = p0 + it * THREADS;     // < NPIX by construction
        const int i = p / IMG;               // row -> Y
        const int j = p - i * IMG;           // col -> X
        const float X = (j - 192.0f) / 5.0f;
        const float Y = (i - 192.0f) / 5.0f;

        const float relx = X - x, rely = Y - yy;
        const float ax =  c * relx + s * rely;
        const float ay = -s * relx + c * rely;
        const float rlx = X - xl, rly = Y - yl;
        const float axl =  c * rlx + s * rly;
        const float ayl = -s * rlx + c * rly;

        const bool mcar   = (fabsf(ax)  <= 5.05f)  && (ay  >= 0.0f) && (ay  <= dy);
        const bool mside  = (fabsf(ax)  <= 1.155f) && (fabsf(ay) <= 2.695f);
        const bool mlight = (fabsf(axl) <= 3.1f)   && (ayl >= 0.0f) && (ayl <= dyl);

        ocar[p]   = mcar   ? 1.0f : 0.0f;
        oside[p]  = mside  ? 1.0f : 0.0f;
        olight[p] = mlight ? 1.0f : 0.0f;

        // mask-gated bev reads: waves fully outside a region skip the loads
        if (mside) {
            aL += (bp[1 * NPIX + p] > 0.5f) ? 1.0f : 0.0f;
            aO += (bp[7 * NPIX + p] > 0.5f) ? 1.0f : 0.0f;
        }
        if (mcar) {
            aV += (bp[2 * NPIX + p] > 0.5f) ? 1.0f : 0.0f;
            aP += (bp[6 * NPIX + p] > 0.5f) ? 1.0f : 0.0f;
        }
        if (mlight) {
            aG += (bp[3 * NPIX + p] > 0.5f) ? 1.0f : 0.0f;
            aY += (bp[4 * NPIX + p] > 0.5f) ? 1.0f : 0.0f;
            aR += (bp[5 * NPIX + p] > 0.5f) ? 1.0f : 0.0f;
        }
    }

    // ---- block reduction of the 7 accumulators ----
    float acc[7] = {aL, aV, aG, aY, aR, aP, aO};
    #pragma unroll
    for (int k = 0; k < 7; ++k) {
        #pragma unroll
        for (int off = 32; off > 0; off >>= 1)
            acc[k] += __shfl_down(acc[k], off, 64);
    }

    __shared__ float red[4][7];
    const int wid = tid >> 6, lane = tid & 63;
    if (lane == 0) {
        #pragma unroll
        for (int k = 0; k < 7; ++k) red[wid][k] = acc[k];
    }
    __syncthreads();
    if (tid < 7) {
        const float v = red[0][tid] + red[1][tid] + red[2][tid] + red[3][tid];
        if (v != 0.0f) {
            const float decay = powf(0.97f, (float)t);
            atomicAdd(&out[tid], v * decay);
        }
    }
}

extern "C" void kernel_launch(void* const* d_in, const int* in_sizes, int n_in,
                              void* d_out, int out_size, void* d_ws, size_t ws_size,
                              hipStream_t stream) {
    const float* loc   = (const float*)d_in[0];
    const float* yaw   = (const float*)d_in[1];
    const float* speed = (const float*)d_in[2];
    const float* bev   = (const float*)d_in[3];
    float* out = (float*)d_out;

    // zero the 7 scalar cost slots (atomics accumulate into them)
    hipMemsetAsync(d_out, 0, 7 * sizeof(float), stream);

    dim3 grid(NBX, NIMG);
    cost_main<<<grid, THREADS, 0, stream>>>(loc, yaw, speed, bev, out);
}

// Round 3
// 52.552 us; speedup vs baseline: 1.3600x; 1.3600x over previous
//
#include <hip/hip_runtime.h>
#include <math.h>

// Problem constants
constexpr int IMG     = 384;
constexpr int NPIX    = IMG * IMG;        // 147456
constexpr int TM1     = 10;               // T-1
constexpr int NIMG    = 80;               // B * (T-1)
constexpr int THREADS = 256;
constexpr int GPT     = 4;                // quad-groups per thread (16 px/thread)
constexpr int GPB     = THREADS * GPT;    // 1024 groups per block
constexpr int NGRP    = NPIX / 4;         // 36864 group slots (last = leftovers)
constexpr int NBX     = NGRP / GPB;       // 36 (exact)
constexpr long long NMASK = (long long)NIMG * NPIX;  // 11,796,480

typedef float v4f __attribute__((ext_vector_type(4)));

// Output layout: [0..6] = 7 scalar costs, then mask_car, mask_side, mask_light

__global__ __launch_bounds__(THREADS) void cost_main(
    const float* __restrict__ loc,    // (8,11,2)
    const float* __restrict__ yaw,    // (8,11,1)
    const float* __restrict__ speed,  // (8,11,1)
    const float* __restrict__ bev,    // (8,11,8,384,384)
    float* __restrict__ out)
{
    const int img = blockIdx.y;          // 0..79
    const int b   = img / TM1;
    const int t   = img - b * TM1;       // bev time index t+1
    const int tid = threadIdx.x;

    // ---- per-image scalars ----
    const float yaw0 = yaw[b * 11];
    const float c0 = cosf(yaw0), s0 = sinf(yaw0);
    const float rx = loc[(b * 11 + t + 1) * 2 + 0] - loc[b * 22 + 0];
    const float ry = loc[(b * 11 + t + 1) * 2 + 1] - loc[b * 22 + 1];
    const float x0 =  c0 * rx + s0 * ry;
    const float y0 = -s0 * rx + c0 * ry;
    const float yw = yaw[b * 11 + t + 1] - yaw0;
    const float c = cosf(yw), s = sinf(yw);
    const float sp  = speed[b * 11 + t + 1];
    const float dy  = 1.5f * (fmaxf(10.0f, sp) + 4.9f) + 1.0f;
    const float dyl = sp * 0.5f + 14.7f;
    const float ox  = 12.0f * c + 3.25f * s;   // light-frame offsets
    const float oy  = 12.0f * s - 3.25f * c;

    const float* bp = bev + (size_t)((b * 11 + t + 1) * 8) * NPIX;
    float* ocar   = out + 7 + (size_t)img * NPIX;
    float* oside  = ocar + NMASK;
    float* olight = ocar + 2 * NMASK;

    float aL = 0.f, aV = 0.f, aG = 0.f, aY = 0.f, aR = 0.f, aP = 0.f, aO = 0.f;

    const int g0 = blockIdx.x * GPB + tid;
    #pragma unroll
    for (int it = 0; it < GPT; ++it) {
        const int g = g0 + it * THREADS;
        if (g != NGRP - 1) {
            const int pb = 4 * g + 1;        // pixels pb..pb+3, 16B-aligned in out
            float mc[4], ms[4], ml[4];
            #pragma unroll
            for (int k = 0; k < 4; ++k) {
                const int p = pb + k;
                const int i = p / IMG;
                const int j = p - i * IMG;
                const float X = (float)j * 0.2f - 38.4f;
                const float Y = (float)i * 0.2f - 38.4f;
                const float relx = X - x0, rely = Y - y0;
                const float ax = c * relx + s * rely;
                const float ay = c * rely - s * relx;
                const float axl = ax - ox, ayl = ay + oy;
                mc[k] = (fabsf(ax)  <= 5.05f  && ay >= 0.f && ay <= dy)   ? 1.f : 0.f;
                ms[k] = (fabsf(ax)  <= 1.155f && fabsf(ay) <= 2.695f)     ? 1.f : 0.f;
                ml[k] = (fabsf(axl) <= 3.1f   && ayl >= 0.f && ayl <= dyl)? 1.f : 0.f;
            }
            v4f vc = {mc[0], mc[1], mc[2], mc[3]};
            v4f vs = {ms[0], ms[1], ms[2], ms[3]};
            v4f vl = {ml[0], ml[1], ml[2], ml[3]};
            __builtin_nontemporal_store(vc, (v4f*)(ocar + pb));
            __builtin_nontemporal_store(vs, (v4f*)(oside + pb));
            __builtin_nontemporal_store(vl, (v4f*)(olight + pb));

            if (ms[0] + ms[1] + ms[2] + ms[3] > 0.f) {
                #pragma unroll
                for (int k = 0; k < 4; ++k) {
                    aL += ms[k] * ((bp[1 * NPIX + pb + k] > 0.5f) ? 1.f : 0.f);
                    aO += ms[k] * ((bp[7 * NPIX + pb + k] > 0.5f) ? 1.f : 0.f);
                }
            }
            if (mc[0] + mc[1] + mc[2] + mc[3] > 0.f) {
                #pragma unroll
                for (int k = 0; k < 4; ++k) {
                    aV += mc[k] * ((bp[2 * NPIX + pb + k] > 0.5f) ? 1.f : 0.f);
                    aP += mc[k] * ((bp[6 * NPIX + pb + k] > 0.5f) ? 1.f : 0.f);
                }
            }
            if (ml[0] + ml[1] + ml[2] + ml[3] > 0.f) {
                #pragma unroll
                for (int k = 0; k < 4; ++k) {
                    aG += ml[k] * ((bp[3 * NPIX + pb + k] > 0.5f) ? 1.f : 0.f);
                    aY += ml[k] * ((bp[4 * NPIX + pb + k] > 0.5f) ? 1.f : 0.f);
                    aR += ml[k] * ((bp[5 * NPIX + pb + k] > 0.5f) ? 1.f : 0.f);
                }
            }
        } else {
            // leftover pixels {0, NPIX-3, NPIX-2, NPIX-1} for this image
            const int pp[4] = {0, NPIX - 3, NPIX - 2, NPIX - 1};
            for (int k = 0; k < 4; ++k) {
                const int p = pp[k];
                const int i = p / IMG;
                const int j = p - i * IMG;
                const float X = (float)j * 0.2f - 38.4f;
                const float Y = (float)i * 0.2f - 38.4f;
                const float relx = X - x0, rely = Y - y0;
                const float ax = c * relx + s * rely;
                const float ay = c * rely - s * relx;
                const float axl = ax - ox, ayl = ay + oy;
                const float mc = (fabsf(ax)  <= 5.05f  && ay >= 0.f && ay <= dy)    ? 1.f : 0.f;
                const float msd= (fabsf(ax)  <= 1.155f && fabsf(ay) <= 2.695f)      ? 1.f : 0.f;
                const float ml = (fabsf(axl) <= 3.1f   && ayl >= 0.f && ayl <= dyl) ? 1.f : 0.f;
                ocar[p] = mc; oside[p] = msd; olight[p] = ml;
                if (msd > 0.f) {
                    aL += (bp[1 * NPIX + p] > 0.5f) ? 1.f : 0.f;
                    aO += (bp[7 * NPIX + p] > 0.5f) ? 1.f : 0.f;
                }
                if (mc > 0.f) {
                    aV += (bp[2 * NPIX + p] > 0.5f) ? 1.f : 0.f;
                    aP += (bp[6 * NPIX + p] > 0.5f) ? 1.f : 0.f;
                }
                if (ml > 0.f) {
                    aG += (bp[3 * NPIX + p] > 0.5f) ? 1.f : 0.f;
                    aY += (bp[4 * NPIX + p] > 0.5f) ? 1.f : 0.f;
                    aR += (bp[5 * NPIX + p] > 0.5f) ? 1.f : 0.f;
                }
            }
        }
    }

    // ---- block reduction of the 7 accumulators ----
    float acc[7] = {aL, aV, aG, aY, aR, aP, aO};
    #pragma unroll
    for (int k = 0; k < 7; ++k) {
        #pragma unroll
        for (int off = 32; off > 0; off >>= 1)
            acc[k] += __shfl_down(acc[k], off, 64);
    }

    __shared__ float red[4][7];
    const int wid = tid >> 6, lane = tid & 63;
    if (lane == 0) {
        #pragma unroll
        for (int k = 0; k < 7; ++k) red[wid][k] = acc[k];
    }
    __syncthreads();
    if (tid < 7) {
        const float v = red[0][tid] + red[1][tid] + red[2][tid] + red[3][tid];
        if (v != 0.0f) {
            float decay = 1.0f;
            for (int q = 0; q < t; ++q) decay *= 0.97f;
            atomicAdd(&out[tid], v * decay);
        }
    }
}

extern "C" void kernel_launch(void* const* d_in, const int* in_sizes, int n_in,
                              void* d_out, int out_size, void* d_ws, size_t ws_size,
                              hipStream_t stream) {
    const float* loc   = (const float*)d_in[0];
    const float* yaw   = (const float*)d_in[1];
    const float* speed = (const float*)d_in[2];
    const float* bev   = (const float*)d_in[3];
    float* out = (float*)d_out;

    // zero the 7 scalar cost slots (atomics accumulate into them)
    (void)hipMemsetAsync(d_out, 0, 7 * sizeof(float), stream);

    dim3 grid(NBX, NIMG);
    cost_main<<<grid, THREADS, 0, stream>>>(loc, yaw, speed, bev, out);
}